// Round 1
// 711.161 us; speedup vs baseline: 1.1169x; 1.1169x over previous
//
#include <hip/hip_runtime.h>
#include <hip/hip_bf16.h>
#include <math.h>

using frag8 = __attribute__((ext_vector_type(8))) short;
using f32x4 = __attribute__((ext_vector_type(4))) float;

#define BM 256
#define BN 256

typedef const __attribute__((address_space(1))) unsigned char glb_u8;
typedef __attribute__((address_space(3))) unsigned char lds_u8;

__device__ __forceinline__ float b2f(unsigned short v) {
    union { unsigned u; float f; } x; x.u = ((unsigned)v) << 16; return x.f;
}
__device__ __forceinline__ unsigned short f2b(float f) {
    union { float f; unsigned u; } x; x.f = f;
    unsigned u = x.u;
    u += 0x7fffu + ((u >> 16) & 1u);   // RNE
    return (unsigned short)(u >> 16);
}

// ---------------- cast fp32 -> bf16 (vectorized) ----------------
__global__ __launch_bounds__(256) void cast_kernel(const float* __restrict__ in,
                                                   unsigned short* __restrict__ out, long n) {
    long i = ((long)blockIdx.x * 256 + threadIdx.x) * 8;
    if (i >= n) return;
    float4 a = *(const float4*)(in + i);
    float4 b = *(const float4*)(in + i + 4);
    struct alignas(16) U8 { unsigned short s[8]; } o;
    o.s[0] = f2b(a.x); o.s[1] = f2b(a.y); o.s[2] = f2b(a.z); o.s[3] = f2b(a.w);
    o.s[4] = f2b(b.x); o.s[5] = f2b(b.y); o.s[6] = f2b(b.z); o.s[7] = f2b(b.w);
    *(U8*)(out + i) = o;
}

// ---------------- transpose + cast: in (R x C) fp32 -> out (C x R) bf16 ----------------
__global__ void transpose_cast(const float* __restrict__ in, unsigned short* __restrict__ out,
                               int R, int Ccols) {
    __shared__ float tile[32][33];
    int bx = blockIdx.x * 32;   // col base in input
    int by = blockIdx.y * 32;   // row base in input
    int tx = threadIdx.x, ty = threadIdx.y;
    for (int r = ty; r < 32; r += 8)
        tile[r][tx] = in[(size_t)(by + r) * Ccols + bx + tx];
    __syncthreads();
    for (int r = ty; r < 32; r += 8)
        out[(size_t)(bx + r) * R + by + tx] = f2b(tile[tx][r]);
}

// ---------------- bf16 MFMA GEMM: C[M,N] = A[M,K] * Bt[N,K]^T ----------------
// 256x256 tile, deep-pipelined ring-4 structure (T3+T4+T5 per the catalog):
//  - K is consumed in 32-wide units; LDS holds 4 units (A 16KB + B 16KB each = 128 KiB).
//  - Each iteration stages unit t+3 with 4x global_load_lds(16B) and computes unit t
//    as two 16-MFMA clusters (m-halves) wrapped in s_setprio(1).
//  - Counted s_waitcnt vmcnt(8) before the raw s_barrier: 12 loads (3 units) stay in
//    flight, only the oldest unit drains -> loads span barriers (never drain to 0
//    in steady state). Safety: unit t+3 overwrites unit t-1's slot, consumed before
//    the iter-(t-1) barrier; unit t+1 readiness fenced by vmcnt(8)+barrier.
//  - LDS layout pair-interleaves rows (two 64B rows per 128B line) with chunk-XOR
//    swizzle c ^= line&7: satisfies global_load_lds's linear-dest constraint via
//    pre-swizzled SOURCE addresses, and ds_read_b128 is conflict-free (uniform
//    8 words/bank across the wave).
// mode 0: store fp32 to Cf
// mode 1: N==3072 split epilogue (block-uniform segment, BN=256 divides 1024):
//         V=gelu, Q=gelu, Lam=lb+(1-lb)*sigmoid, all bf16.
__global__ __launch_bounds__(512, 2) void gemm_bf16(
    const unsigned short* __restrict__ A, const unsigned short* __restrict__ Bt,
    int M, int N, int K, int mode,
    float* __restrict__ Cf,
    unsigned short* __restrict__ Vp, unsigned short* __restrict__ Qp,
    unsigned short* __restrict__ Lp, const float* __restrict__ lb) {
    __shared__ __align__(16) char smem[131072];   // 4 units x (16KB A + 16KB B)

    const int tid = threadIdx.x;
    const int lane16 = tid & 15;
    const int quad = (tid >> 4) & 3;
    const int wave = tid >> 6;
    const int wm = wave >> 2;        // 0..1 -> 128-row half
    const int wn = wave & 3;         // 0..3 -> 64-col slice

    // XCD-aware bijective swizzle (nwg % 8 == 0 for both our launches)
    const int nbx = N / BN;
    const int nwg = (int)gridDim.x;
    const int sw = ((int)blockIdx.x & 7) * (nwg >> 3) + ((int)blockIdx.x >> 3);
    const long m0 = (long)(sw / nbx) * BM;
    const long n0 = (long)(sw % nbx) * BN;
    const long K2 = (long)K * 2;

    // ---- staging addresses (identical pattern for A and B) ----
    // load L in {0,1} writes LDS bytes [L*8192 + tid*16, +16) of the unit region.
    // line = off/128, chunk c = (off/16)&7; logical chunk c0 = c ^ (line&7);
    // line i holds rows {2i, 2i+1}: c0 = rowpar*4 + kblk (kblk = 8-elem group of k).
    const int c0 = (tid & 7) ^ ((tid >> 3) & 7);
    long srcL0, srcL1; int dstL0, dstL1;
    {
        const int kk2 = (c0 & 3) << 4;                      // byte offset of k-group
        const int r0 = ((tid >> 3) << 1) + (c0 >> 2);       // rows 0..127
        const int r1 = ((64 + (tid >> 3)) << 1) + (c0 >> 2);// rows 128..255
        srcL0 = (long)r0 * K2 + kk2;
        srcL1 = (long)r1 * K2 + kk2;
        dstL0 = tid * 16;
        dstL1 = 8192 + tid * 16;
    }
    const char* Ab = (const char*)A + m0 * K2;
    const char* Bb = (const char*)Bt + n0 * K2;

    // ---- fragment read offsets within a unit (bytes), constant across K ----
    int offA[8], offB[4];
#pragma unroll
    for (int mf = 0; mf < 8; ++mf) {
        int row = wm * 128 + mf * 16 + lane16;
        int line = row >> 1;
        int c = (((row & 1) << 2) | quad) ^ (line & 7);
        offA[mf] = line * 128 + c * 16;
    }
#pragma unroll
    for (int nf = 0; nf < 4; ++nf) {
        int row = wn * 64 + nf * 16 + lane16;
        int line = row >> 1;
        int c = (((row & 1) << 2) | quad) ^ (line & 7);
        offB[nf] = 16384 + line * 128 + c * 16;
    }

    f32x4 acc[8][4];
#pragma unroll
    for (int i = 0; i < 8; ++i)
#pragma unroll
        for (int j = 0; j < 4; ++j) acc[i][j] = (f32x4){0.f, 0.f, 0.f, 0.f};

#define STAGE(u) do { \
        char* ldb = smem + ((u) & 3) * 32768; \
        long kb = (long)(u) * 64; \
        __builtin_amdgcn_global_load_lds((glb_u8*)(Ab + srcL0 + kb), (lds_u8*)(ldb + dstL0), 16, 0, 0); \
        __builtin_amdgcn_global_load_lds((glb_u8*)(Ab + srcL1 + kb), (lds_u8*)(ldb + dstL1), 16, 0, 0); \
        __builtin_amdgcn_global_load_lds((glb_u8*)(Bb + srcL0 + kb), (lds_u8*)(ldb + 16384 + dstL0), 16, 0, 0); \
        __builtin_amdgcn_global_load_lds((glb_u8*)(Bb + srcL1 + kb), (lds_u8*)(ldb + 16384 + dstL1), 16, 0, 0); \
    } while (0)

    const int NT = K >> 5;   // 32-wide K-units
    // prologue: fill 3 units of the ring; drain only the oldest
    STAGE(0); STAGE(1); STAGE(2);
    asm volatile("s_waitcnt vmcnt(8)" ::: "memory");
    __builtin_amdgcn_s_barrier();

    for (int t = 0; t < NT; ++t) {
        if (t + 3 < NT) STAGE(t + 3);
        const char* ub = smem + (t & 3) * 32768;
        frag8 bfr[4], af[4];
#pragma unroll
        for (int nf = 0; nf < 4; ++nf) bfr[nf] = *(const frag8*)(ub + offB[nf]);
#pragma unroll
        for (int mf = 0; mf < 4; ++mf) af[mf] = *(const frag8*)(ub + offA[mf]);
        __builtin_amdgcn_s_setprio(1);
#pragma unroll
        for (int mf = 0; mf < 4; ++mf)
#pragma unroll
            for (int nf = 0; nf < 4; ++nf)
                acc[mf][nf] = __builtin_amdgcn_mfma_f32_16x16x32_bf16(af[mf], bfr[nf], acc[mf][nf], 0, 0, 0);
        __builtin_amdgcn_s_setprio(0);
#pragma unroll
        for (int mf = 0; mf < 4; ++mf) af[mf] = *(const frag8*)(ub + offA[4 + mf]);
        __builtin_amdgcn_s_setprio(1);
#pragma unroll
        for (int mf = 0; mf < 4; ++mf)
#pragma unroll
            for (int nf = 0; nf < 4; ++nf)
                acc[4 + mf][nf] = __builtin_amdgcn_mfma_f32_16x16x32_bf16(af[mf], bfr[nf], acc[4 + mf][nf], 0, 0, 0);
        __builtin_amdgcn_s_setprio(0);
        // counted fence: guarantee unit t+1 landed; keep 2 units in flight
        if (t < NT - 3)       { asm volatile("s_waitcnt vmcnt(8)" ::: "memory"); }
        else if (t == NT - 3) { asm volatile("s_waitcnt vmcnt(4)" ::: "memory"); }
        else if (t == NT - 2) { asm volatile("s_waitcnt vmcnt(0)" ::: "memory"); }
        __builtin_amdgcn_s_barrier();
    }
#undef STAGE

    if (mode == 0) {
#pragma unroll
        for (int mf = 0; mf < 8; ++mf)
#pragma unroll
            for (int nf = 0; nf < 4; ++nf) {
                long col = n0 + wn * 64 + nf * 16 + lane16;
#pragma unroll
                for (int r = 0; r < 4; ++r) {
                    long row = m0 + wm * 128 + mf * 16 + quad * 4 + r;
                    Cf[row * N + col] = acc[mf][nf][r];
                }
            }
    } else {
        // block-uniform segment: BN=256 divides 1024, so each block is in one segment
        const int seg = (int)(n0 >> 10);            // 0=V, 1=Q, 2=Lam
        const int cbase = (int)(n0 & 1023) + wn * 64;
        unsigned short* dst = (seg == 0) ? Vp : (seg == 1 ? Qp : Lp);
#pragma unroll
        for (int mf = 0; mf < 8; ++mf)
#pragma unroll
            for (int nf = 0; nf < 4; ++nf) {
                int col = cbase + nf * 16 + lane16;
#pragma unroll
                for (int r = 0; r < 4; ++r) {
                    long row = m0 + wm * 128 + mf * 16 + quad * 4 + r;
                    float v = acc[mf][nf][r];
                    float res;
                    if (seg < 2) {
                        // tanh-form gelu: x * sigmoid(1.5958*x*(1+0.044715 x^2))
                        float u = 1.59576912f * v * (1.0f + 0.044715f * v * v);
                        res = v / (1.0f + __expf(-u));
                    } else {
                        float sg = 1.0f / (1.0f + __expf(-v));
                        float l = lb[col];
                        res = l + (1.0f - l) * sg;
                    }
                    dst[row * 1024 + col] = f2b(res);
                }
            }
    }
}

// ---------------- scan phase 1: per-(chain,chunk) local state + decay product ----------------
__global__ __launch_bounds__(256) void scan_phase1(
    const unsigned short* __restrict__ lam, const unsigned short* __restrict__ V,
    float* __restrict__ Sl, float* __restrict__ P, int L) {
    int cid = blockIdx.x * 256 + threadIdx.x;  // 0..4095
    int c = blockIdx.y;
    int bi = cid >> 9, h = cid & 511;
    float s00 = 0, s01 = 0, s10 = 0, s11 = 0, p0 = 1.f, p1 = 1.f;
    int t0 = c * L;
    const unsigned* lamp = (const unsigned*)lam;
    const unsigned* vp = (const unsigned*)V;
    for (int t = t0; t < t0 + L; ++t) {
        long idx = (long)(t * 8 + bi) * 512 + h;
        unsigned lu = lamp[idx], vu = vp[idx];
        float la0 = b2f((unsigned short)lu), la1 = b2f((unsigned short)(lu >> 16));
        float v0 = b2f((unsigned short)vu), v1 = b2f((unsigned short)(vu >> 16));
        float k0 = 1.f - la0, k1 = 1.f - la1;
        s00 = fmaf(la0, s00, k0 * v0); s01 = fmaf(la0, s01, k0 * v1);
        s10 = fmaf(la1, s10, k1 * v0); s11 = fmaf(la1, s11, k1 * v1);
        p0 *= la0; p1 *= la1;
    }
    long base = (long)c * 4096 + cid;
    ((float4*)Sl)[base] = make_float4(s00, s01, s10, s11);
    ((float2*)P)[base] = make_float2(p0, p1);
}

// ---------------- scan phase 2: sequential combine over chunks ----------------
__global__ __launch_bounds__(256) void scan_phase2(
    const float* __restrict__ Sl, const float* __restrict__ P,
    float* __restrict__ Sini, int C) {
    int idx = blockIdx.x * 256 + threadIdx.x;  // 0..16383
    int cid = idx >> 2, ij = idx & 3, i = (idx >> 1) & 1;
    float s = 0.f;
    for (int c = 0; c < C; ++c) {
        long base = (long)c * 4096 + cid;
        Sini[base * 4 + ij] = s;
        s = fmaf(P[base * 2 + i], s, Sl[base * 4 + ij]);
    }
}

// ---------------- scan phase 3: replay with seeded state, emit o ----------------
__global__ __launch_bounds__(256) void scan_phase3(
    const unsigned short* __restrict__ lam, const unsigned short* __restrict__ V,
    const unsigned short* __restrict__ Q, const float* __restrict__ Sini,
    unsigned short* __restrict__ o, int L) {
    int cid = blockIdx.x * 256 + threadIdx.x;
    int c = blockIdx.y;
    int bi = cid >> 9, h = cid & 511;
    float4 si = ((const float4*)Sini)[(long)c * 4096 + cid];
    float s00 = si.x, s01 = si.y, s10 = si.z, s11 = si.w;
    int t0 = c * L;
    const unsigned* lamp = (const unsigned*)lam;
    const unsigned* vp = (const unsigned*)V;
    const unsigned* qp = (const unsigned*)Q;
    unsigned* op = (unsigned*)o;
    for (int t = t0; t < t0 + L; ++t) {
        long idx = (long)(t * 8 + bi) * 512 + h;
        unsigned lu = lamp[idx], vu = vp[idx], qu = qp[idx];
        float la0 = b2f((unsigned short)lu), la1 = b2f((unsigned short)(lu >> 16));
        float v0 = b2f((unsigned short)vu), v1 = b2f((unsigned short)(vu >> 16));
        float q0 = b2f((unsigned short)qu), q1 = b2f((unsigned short)(qu >> 16));
        float k0 = 1.f - la0, k1 = 1.f - la1;
        s00 = fmaf(la0, s00, k0 * v0); s01 = fmaf(la0, s01, k0 * v1);
        s10 = fmaf(la1, s10, k1 * v0); s11 = fmaf(la1, s11, k1 * v1);
        float o0 = q0 * s00 + q1 * s10;
        float o1 = q0 * s01 + q1 * s11;
        op[idx] = (unsigned)f2b(o0) | ((unsigned)f2b(o1) << 16);
    }
}

extern "C" void kernel_launch(void* const* d_in, const int* in_sizes, int n_in,
                              void* d_out, int out_size, void* d_ws, size_t ws_size,
                              hipStream_t stream) {
    const float* x = (const float*)d_in[0];
    const float* lb = (const float*)d_in[1];
    const float* W_in = (const float*)d_in[2];
    const float* W_out = (const float*)d_in[3];
    float* out = (float*)d_out;

    const int n = 4096, b = 8, d = 1024;
    const long NB = (long)n * b;   // 32768 rows
    const int C = 64, L = 64;      // chunks x chunk length (C*L == n)

    char* ws = (char*)d_ws;
    size_t off = 0;
    auto alloc = [&](size_t bytes) -> char* {
        char* p = ws + off;
        off += (bytes + 255) & ~(size_t)255;
        return p;
    };
    unsigned short* xb   = (unsigned short*)alloc(NB * d * 2);          // reused as o after GEMM1
    unsigned short* Wint = (unsigned short*)alloc((size_t)3 * d * d * 2);
    unsigned short* Wot  = (unsigned short*)alloc((size_t)d * d * 2);
    unsigned short* Vb   = (unsigned short*)alloc(NB * d * 2);
    unsigned short* Qb   = (unsigned short*)alloc(NB * d * 2);
    unsigned short* Lb   = (unsigned short*)alloc(NB * d * 2);
    float* Sl   = (float*)alloc((size_t)C * 4096 * 4 * 4);
    float* P    = (float*)alloc((size_t)C * 4096 * 2 * 4);
    float* Sini = (float*)alloc((size_t)C * 4096 * 4 * 4);

    // 1) cast x -> bf16
    cast_kernel<<<dim3((unsigned)((NB * d) / (256 * 8))), 256, 0, stream>>>(x, xb, NB * d);
    // 2) transpose+cast weights (so GEMM B operand is K-contiguous)
    transpose_cast<<<dim3(3 * d / 32, d / 32), dim3(32, 8), 0, stream>>>(W_in, Wint, d, 3 * d);
    transpose_cast<<<dim3(d / 32, d / 32), dim3(32, 8), 0, stream>>>(W_out, Wot, d, d);
    // 3) GEMM1 + fused activations -> V, Q, lam (bf16); 256x256 tiles, 512 threads
    const int nwg1 = (3 * d / BN) * (int)(NB / BM);   // 12 * 128 = 1536 (%8==0)
    gemm_bf16<<<dim3(nwg1), 512, 0, stream>>>(
        xb, Wint, (int)NB, 3 * d, d, 1, nullptr, Vb, Qb, Lb, lb);
    // 4) chunked scan
    scan_phase1<<<dim3(16, C), 256, 0, stream>>>(Lb, Vb, Sl, P, L);
    scan_phase2<<<dim3(64), 256, 0, stream>>>(Sl, P, Sini, C);
    unsigned short* ob = xb;  // xb dead after GEMM1; reuse as o
    scan_phase3<<<dim3(16, C), 256, 0, stream>>>(Lb, Vb, Qb, Sini, ob, L);
    // 5) GEMM2 -> fp32 output
    const int nwg2 = (d / BN) * (int)(NB / BM);       // 4 * 128 = 512 (%8==0)
    gemm_bf16<<<dim3(nwg2), 512, 0, stream>>>(
        ob, Wot, (int)NB, d, d, 0, out, nullptr, nullptr, nullptr, nullptr);
}

// Round 2
// 706.720 us; speedup vs baseline: 1.1240x; 1.0063x over previous
//
#include <hip/hip_runtime.h>
#include <hip/hip_bf16.h>
#include <math.h>

using frag8 = __attribute__((ext_vector_type(8))) short;
using f32x4 = __attribute__((ext_vector_type(4))) float;

#define BM 256
#define BN 256

typedef const __attribute__((address_space(1))) unsigned char glb_u8;
typedef __attribute__((address_space(3))) unsigned char lds_u8;

__device__ __forceinline__ float b2f(unsigned short v) {
    union { unsigned u; float f; } x; x.u = ((unsigned)v) << 16; return x.f;
}
__device__ __forceinline__ unsigned short f2b(float f) {
    union { float f; unsigned u; } x; x.f = f;
    unsigned u = x.u;
    u += 0x7fffu + ((u >> 16) & 1u);   // RNE
    return (unsigned short)(u >> 16);
}

// ---------------- cast fp32 -> bf16 (vectorized) ----------------
__global__ __launch_bounds__(256) void cast_kernel(const float* __restrict__ in,
                                                   unsigned short* __restrict__ out, long n) {
    long i = ((long)blockIdx.x * 256 + threadIdx.x) * 8;
    if (i >= n) return;
    float4 a = *(const float4*)(in + i);
    float4 b = *(const float4*)(in + i + 4);
    struct alignas(16) U8 { unsigned short s[8]; } o;
    o.s[0] = f2b(a.x); o.s[1] = f2b(a.y); o.s[2] = f2b(a.z); o.s[3] = f2b(a.w);
    o.s[4] = f2b(b.x); o.s[5] = f2b(b.y); o.s[6] = f2b(b.z); o.s[7] = f2b(b.w);
    *(U8*)(out + i) = o;
}

// ---------------- transpose + cast: in (R x C) fp32 -> out (C x R) bf16 ----------------
__global__ void transpose_cast(const float* __restrict__ in, unsigned short* __restrict__ out,
                               int R, int Ccols) {
    __shared__ float tile[32][33];
    int bx = blockIdx.x * 32;   // col base in input
    int by = blockIdx.y * 32;   // row base in input
    int tx = threadIdx.x, ty = threadIdx.y;
    for (int r = ty; r < 32; r += 8)
        tile[r][tx] = in[(size_t)(by + r) * Ccols + bx + tx];
    __syncthreads();
    for (int r = ty; r < 32; r += 8)
        out[(size_t)(bx + r) * R + by + tx] = f2b(tile[tx][r]);
}

// ---------------- bf16 MFMA GEMM: C[M,N] = A[M,K] * Bt[N,K]^T ----------------
// m201-style 8-phase schedule, 256x256 tile, BK=64, 2 K-tile LDS buffers (128 KiB).
// Per phase: [stage one 16KB half-tile (2x global_load_lds)] [vmcnt(2) at ph4/8 only]
// [issue NEXT phase's ds_read_b128 frags] [barrier] [setprio(1) 16 MFMA setprio(0)]
// [barrier]. Reads run one phase ahead of their consuming MFMA; counted vmcnt keeps
// 2 loads in flight across the fence (never drains to 0 mid-loop). Cross-wave
// publish is always vmcnt -> barrier -> read (vmcnt is per-wave). A buffer region
// is restaged >= 1 phase + barrier after its last read ISSUE (plus >=300cy VMEM
// latency margin), matching the template's hazard discipline.
// LDS: BK=64 -> one row = 128B = one line of 8 chunks; chunk' = chunk ^ (row&7)
// (applied on the pre-swizzled global SOURCE; read side XORs the same way ->
// bank-conflict-free ds_read_b128, verified 0 conflicts in prior rounds).
// mode 0: store fp32 to Cf
// mode 1: N==3072 split epilogue (block-uniform segment, BN=256 divides 1024):
//         V=gelu, Q=gelu, Lam=lb+(1-lb)*sigmoid, all bf16.
__global__ __launch_bounds__(512, 2) void gemm_bf16(
    const unsigned short* __restrict__ A, const unsigned short* __restrict__ Bt,
    int M, int N, int K, int mode,
    float* __restrict__ Cf,
    unsigned short* __restrict__ Vp, unsigned short* __restrict__ Qp,
    unsigned short* __restrict__ Lp, const float* __restrict__ lb) {
    __shared__ __align__(16) char smem[131072];   // buf0: [A0 A1 B0 B1] buf1: +65536

    const int tid = threadIdx.x;
    const int lane16 = tid & 15;
    const int quad = (tid >> 4) & 3;
    const int wave = tid >> 6;
    const int wm = wave >> 2;        // 0..1 -> 128-row half of C
    const int wn = wave & 3;         // 0..3 -> 64-col slice of C

    // XCD-aware bijective swizzle (nwg % 8 == 0 for both launches)
    const int nbx = N / BN;
    const int nwg = (int)gridDim.x;
    const int sw = ((int)blockIdx.x & 7) * (nwg >> 3) + ((int)blockIdx.x >> 3);
    const long m0 = (long)(sw / nbx) * BM;
    const long n0 = (long)(sw % nbx) * BN;
    const long K2 = (long)K * 2;

    // ---- staging addresses: thread covers chunk (tid&7) of line (tid>>3) ----
    // logical (global) chunk c0 = (tid&7) ^ (line&7); two loads per half-tile
    // (L=0: lines 0..63 = rows 0..63 of the half; L=1: +64 rows).
    const int c16 = (((tid & 7) ^ ((tid >> 3) & 7)) << 4);
    const long o64 = 64 * K2, o128 = 128 * K2;
    const char* Ab = (const char*)A + m0 * K2;
    const char* Bb = (const char*)Bt + n0 * K2;
    const char* pA0 = Ab + (long)(tid >> 3) * K2 + c16;   // A half 0
    const char* pA1 = pA0 + o128;                          // A half 1
    const char* pB0 = Bb + (long)(tid >> 3) * K2 + c16;   // B half 0
    const char* pB1 = pB0 + o128;                          // B half 1
    const int dst0 = tid * 16;

    // ---- fragment read bases (bytes); mf/nf steps fold into ds_read imm offs ----
    // row&7 == lane16&7 for every fragment row -> only two swizzle values/thread.
    const int baseA = wm * 16384 + lane16 * 128;
    const int baseB = 32768 + (wn >> 1) * 16384 + (wn & 1) * 8192 + lane16 * 128;
    const int swz0 = ((quad ^ (lane16 & 7)) << 4);
    const int swz1 = (((4 + quad) ^ (lane16 & 7)) << 4);

    f32x4 acc[8][4];
#pragma unroll
    for (int i = 0; i < 8; ++i)
#pragma unroll
        for (int j = 0; j < 4; ++j) acc[i][j] = (f32x4){0.f, 0.f, 0.f, 0.f};
    frag8 a0[4], a1[4], b0[4], b1[4];

#define STAGE(P, R, KO) do { \
        __builtin_amdgcn_global_load_lds((glb_u8*)((P) + (KO)), \
            (lds_u8*)(smem + (R) + dst0), 16, 0, 0); \
        __builtin_amdgcn_global_load_lds((glb_u8*)((P) + o64 + (KO)), \
            (lds_u8*)(smem + (R) + 8192 + dst0), 16, 0, 0); \
    } while (0)
#define RD4(D, BUF, BASE, SW) do { \
        D[0] = *(const frag8*)(smem + (BUF) + (BASE) + (SW)); \
        D[1] = *(const frag8*)(smem + (BUF) + (BASE) + 2048 + (SW)); \
        D[2] = *(const frag8*)(smem + (BUF) + (BASE) + 4096 + (SW)); \
        D[3] = *(const frag8*)(smem + (BUF) + (BASE) + 6144 + (SW)); \
    } while (0)
#define MM(AF, BF, RO) do { \
        _Pragma("unroll") \
        for (int _m = 0; _m < 4; ++_m) \
            _Pragma("unroll") \
            for (int _n = 0; _n < 4; ++_n) \
                acc[(RO) + _m][_n] = __builtin_amdgcn_mfma_f32_16x16x32_bf16( \
                    AF[_m], BF[_n], acc[(RO) + _m][_n], 0, 0, 0); \
    } while (0)
#define VM2 asm volatile("s_waitcnt vmcnt(2)" ::: "memory")
#define VM0 asm volatile("s_waitcnt vmcnt(0)" ::: "memory")
#define BARR __builtin_amdgcn_s_barrier()
#define PRIO1 __builtin_amdgcn_s_setprio(1)
#define PRIO0 __builtin_amdgcn_s_setprio(0)

    // ---- prologue: tile0 (all 4 halves) -> buf0, tile1 Ah0 -> buf1 ----
    STAGE(pA0, 0, 0); STAGE(pA1, 16384, 0); STAGE(pB0, 32768, 0); STAGE(pB1, 49152, 0);
    STAGE(pA0, 65536, 128);
    VM2; BARR;                             // tile0 published (2 loads stay in flight)
    RD4(a0, 0, baseA, swz0); RD4(b0, 0, baseB, swz0);

    long ko = 0;                           // tile u <-> byte offset u*128
    const int NI = K >> 7;                 // iterations, 2 K-tiles (BK=64) each
    for (int i = 0; i < NI - 1; ++i, ko += 256) {
        // ph1: MFMA(a0,b0|ks0,lo)   stage Ah1(t+1)->buf1   read a1 (ks0,hi)
        STAGE(pA1, 65536 + 16384, ko + 128);
        RD4(a1, 0, baseA + 8192, swz0);
        BARR; PRIO1; MM(a0, b0, 0); PRIO0; BARR;
        // ph2: MFMA(a1,b0)          stage Bh0(t+1)         read a0,b1 (ks1,lo)
        STAGE(pB0, 65536 + 32768, ko + 128);
        RD4(a0, 0, baseA, swz1); RD4(b1, 0, baseB, swz1);
        BARR; PRIO1; MM(a1, b0, 4); PRIO0; BARR;
        // ph3: MFMA(a0,b1)          stage Bh1(t+1)         read a1 (ks1,hi)
        STAGE(pB1, 65536 + 49152, ko + 128);
        RD4(a1, 0, baseA + 8192, swz1);
        BARR; PRIO1; MM(a0, b1, 0); PRIO0; BARR;
        // ph4: FENCE tile t+1; MFMA(a1,b1); stage Ah0(t+2)->buf0; read buf1 ks0,lo
        STAGE(pA0, 0, ko + 256);
        VM2; BARR;
        RD4(a0, 65536, baseA, swz0); RD4(b0, 65536, baseB, swz0);
        PRIO1; MM(a1, b1, 4); PRIO0; BARR;
        // ph5..ph7: same pattern on buf1, staging tile t+2 into buf0
        STAGE(pA1, 16384, ko + 256);
        RD4(a1, 65536, baseA + 8192, swz0);
        BARR; PRIO1; MM(a0, b0, 0); PRIO0; BARR;
        STAGE(pB0, 32768, ko + 256);
        RD4(a0, 65536, baseA, swz1); RD4(b1, 65536, baseB, swz1);
        BARR; PRIO1; MM(a1, b0, 4); PRIO0; BARR;
        STAGE(pB1, 49152, ko + 256);
        RD4(a1, 65536, baseA + 8192, swz1);
        BARR; PRIO1; MM(a0, b1, 0); PRIO0; BARR;
        // ph8: FENCE tile t+2; MFMA(a1,b1); stage Ah0(t+3)->buf1; read buf0 ks0,lo
        STAGE(pA0, 65536, ko + 384);
        VM2; BARR;
        RD4(a0, 0, baseA, swz0); RD4(b0, 0, baseB, swz0);
        PRIO1; MM(a1, b1, 4); PRIO0; BARR;
    }
    // ---- peeled last iteration: tiles NT-2 (buf0), NT-1 (buf1) ----
    STAGE(pA1, 65536 + 16384, ko + 128);
    RD4(a1, 0, baseA + 8192, swz0);
    BARR; PRIO1; MM(a0, b0, 0); PRIO0; BARR;
    STAGE(pB0, 65536 + 32768, ko + 128);
    RD4(a0, 0, baseA, swz1); RD4(b1, 0, baseB, swz1);
    BARR; PRIO1; MM(a1, b0, 4); PRIO0; BARR;
    STAGE(pB1, 65536 + 49152, ko + 128);
    RD4(a1, 0, baseA + 8192, swz1);
    BARR; PRIO1; MM(a0, b1, 0); PRIO0; BARR;
    VM0; BARR;                             // publish tile NT-1 (tail: drain all)
    RD4(a0, 65536, baseA, swz0); RD4(b0, 65536, baseB, swz0);
    PRIO1; MM(a1, b1, 4); PRIO0; BARR;
    RD4(a1, 65536, baseA + 8192, swz0);
    BARR; PRIO1; MM(a0, b0, 0); PRIO0; BARR;
    RD4(a0, 65536, baseA, swz1); RD4(b1, 65536, baseB, swz1);
    BARR; PRIO1; MM(a1, b0, 4); PRIO0; BARR;
    RD4(a1, 65536, baseA + 8192, swz1);
    BARR; PRIO1; MM(a0, b1, 0); PRIO0; BARR;
    PRIO1; MM(a1, b1, 4); PRIO0;
#undef STAGE
#undef RD4
#undef MM
#undef VM2
#undef VM0
#undef BARR
#undef PRIO1
#undef PRIO0

    if (mode == 0) {
#pragma unroll
        for (int mf = 0; mf < 8; ++mf)
#pragma unroll
            for (int nf = 0; nf < 4; ++nf) {
                long col = n0 + wn * 64 + nf * 16 + lane16;
#pragma unroll
                for (int r = 0; r < 4; ++r) {
                    long row = m0 + wm * 128 + mf * 16 + quad * 4 + r;
                    Cf[row * N + col] = acc[mf][nf][r];
                }
            }
    } else {
        // block-uniform segment: BN=256 divides 1024, so each block is in one segment
        const int seg = (int)(n0 >> 10);            // 0=V, 1=Q, 2=Lam
        const int cbase = (int)(n0 & 1023) + wn * 64;
        unsigned short* dst = (seg == 0) ? Vp : (seg == 1 ? Qp : Lp);
#pragma unroll
        for (int mf = 0; mf < 8; ++mf)
#pragma unroll
            for (int nf = 0; nf < 4; ++nf) {
                int col = cbase + nf * 16 + lane16;
#pragma unroll
                for (int r = 0; r < 4; ++r) {
                    long row = m0 + wm * 128 + mf * 16 + quad * 4 + r;
                    float v = acc[mf][nf][r];
                    float res;
                    if (seg < 2) {
                        // tanh-form gelu: x * sigmoid(1.5958*x*(1+0.044715 x^2))
                        float u = 1.59576912f * v * (1.0f + 0.044715f * v * v);
                        res = v / (1.0f + __expf(-u));
                    } else {
                        float sg = 1.0f / (1.0f + __expf(-v));
                        float l = lb[col];
                        res = l + (1.0f - l) * sg;
                    }
                    dst[row * 1024 + col] = f2b(res);
                }
            }
    }
}

// ---------------- scan phase 1: per-(chain,chunk) local state + decay product ----------------
__global__ __launch_bounds__(256) void scan_phase1(
    const unsigned short* __restrict__ lam, const unsigned short* __restrict__ V,
    float* __restrict__ Sl, float* __restrict__ P, int L) {
    int cid = blockIdx.x * 256 + threadIdx.x;  // 0..4095
    int c = blockIdx.y;
    int bi = cid >> 9, h = cid & 511;
    float s00 = 0, s01 = 0, s10 = 0, s11 = 0, p0 = 1.f, p1 = 1.f;
    int t0 = c * L;
    const unsigned* lamp = (const unsigned*)lam;
    const unsigned* vp = (const unsigned*)V;
    for (int t = t0; t < t0 + L; ++t) {
        long idx = (long)(t * 8 + bi) * 512 + h;
        unsigned lu = lamp[idx], vu = vp[idx];
        float la0 = b2f((unsigned short)lu), la1 = b2f((unsigned short)(lu >> 16));
        float v0 = b2f((unsigned short)vu), v1 = b2f((unsigned short)(vu >> 16));
        float k0 = 1.f - la0, k1 = 1.f - la1;
        s00 = fmaf(la0, s00, k0 * v0); s01 = fmaf(la0, s01, k0 * v1);
        s10 = fmaf(la1, s10, k1 * v0); s11 = fmaf(la1, s11, k1 * v1);
        p0 *= la0; p1 *= la1;
    }
    long base = (long)c * 4096 + cid;
    ((float4*)Sl)[base] = make_float4(s00, s01, s10, s11);
    ((float2*)P)[base] = make_float2(p0, p1);
}

// ---------------- scan phase 2: sequential combine over chunks ----------------
__global__ __launch_bounds__(256) void scan_phase2(
    const float* __restrict__ Sl, const float* __restrict__ P,
    float* __restrict__ Sini, int C) {
    int idx = blockIdx.x * 256 + threadIdx.x;  // 0..16383
    int cid = idx >> 2, ij = idx & 3, i = (idx >> 1) & 1;
    float s = 0.f;
    for (int c = 0; c < C; ++c) {
        long base = (long)c * 4096 + cid;
        Sini[base * 4 + ij] = s;
        s = fmaf(P[base * 2 + i], s, Sl[base * 4 + ij]);
    }
}

// ---------------- scan phase 3: replay with seeded state, emit o ----------------
__global__ __launch_bounds__(256) void scan_phase3(
    const unsigned short* __restrict__ lam, const unsigned short* __restrict__ V,
    const unsigned short* __restrict__ Q, const float* __restrict__ Sini,
    unsigned short* __restrict__ o, int L) {
    int cid = blockIdx.x * 256 + threadIdx.x;
    int c = blockIdx.y;
    int bi = cid >> 9, h = cid & 511;
    float4 si = ((const float4*)Sini)[(long)c * 4096 + cid];
    float s00 = si.x, s01 = si.y, s10 = si.z, s11 = si.w;
    int t0 = c * L;
    const unsigned* lamp = (const unsigned*)lam;
    const unsigned* vp = (const unsigned*)V;
    const unsigned* qp = (const unsigned*)Q;
    unsigned* op = (unsigned*)o;
    for (int t = t0; t < t0 + L; ++t) {
        long idx = (long)(t * 8 + bi) * 512 + h;
        unsigned lu = lamp[idx], vu = vp[idx], qu = qp[idx];
        float la0 = b2f((unsigned short)lu), la1 = b2f((unsigned short)(lu >> 16));
        float v0 = b2f((unsigned short)vu), v1 = b2f((unsigned short)(vu >> 16));
        float q0 = b2f((unsigned short)qu), q1 = b2f((unsigned short)(qu >> 16));
        float k0 = 1.f - la0, k1 = 1.f - la1;
        s00 = fmaf(la0, s00, k0 * v0); s01 = fmaf(la0, s01, k0 * v1);
        s10 = fmaf(la1, s10, k1 * v0); s11 = fmaf(la1, s11, k1 * v1);
        float o0 = q0 * s00 + q1 * s10;
        float o1 = q0 * s01 + q1 * s11;
        op[idx] = (unsigned)f2b(o0) | ((unsigned)f2b(o1) << 16);
    }
}

extern "C" void kernel_launch(void* const* d_in, const int* in_sizes, int n_in,
                              void* d_out, int out_size, void* d_ws, size_t ws_size,
                              hipStream_t stream) {
    const float* x = (const float*)d_in[0];
    const float* lb = (const float*)d_in[1];
    const float* W_in = (const float*)d_in[2];
    const float* W_out = (const float*)d_in[3];
    float* out = (float*)d_out;

    const int n = 4096, b = 8, d = 1024;
    const long NB = (long)n * b;   // 32768 rows
    const int C = 64, L = 64;      // chunks x chunk length (C*L == n)

    char* ws = (char*)d_ws;
    size_t off = 0;
    auto alloc = [&](size_t bytes) -> char* {
        char* p = ws + off;
        off += (bytes + 255) & ~(size_t)255;
        return p;
    };
    unsigned short* xb   = (unsigned short*)alloc(NB * d * 2);          // reused as o after GEMM1
    unsigned short* Wint = (unsigned short*)alloc((size_t)3 * d * d * 2);
    unsigned short* Wot  = (unsigned short*)alloc((size_t)d * d * 2);
    unsigned short* Vb   = (unsigned short*)alloc(NB * d * 2);
    unsigned short* Qb   = (unsigned short*)alloc(NB * d * 2);
    unsigned short* Lb   = (unsigned short*)alloc(NB * d * 2);
    float* Sl   = (float*)alloc((size_t)C * 4096 * 4 * 4);
    float* P    = (float*)alloc((size_t)C * 4096 * 2 * 4);
    float* Sini = (float*)alloc((size_t)C * 4096 * 4 * 4);

    // 1) cast x -> bf16
    cast_kernel<<<dim3((unsigned)((NB * d) / (256 * 8))), 256, 0, stream>>>(x, xb, NB * d);
    // 2) transpose+cast weights (so GEMM B operand is K-contiguous)
    transpose_cast<<<dim3(3 * d / 32, d / 32), dim3(32, 8), 0, stream>>>(W_in, Wint, d, 3 * d);
    transpose_cast<<<dim3(d / 32, d / 32), dim3(32, 8), 0, stream>>>(W_out, Wot, d, d);
    // 3) GEMM1 + fused activations -> V, Q, lam (bf16); 256x256 tiles, 512 threads
    const int nwg1 = (3 * d / BN) * (int)(NB / BM);   // 12 * 128 = 1536 (%8==0)
    gemm_bf16<<<dim3(nwg1), 512, 0, stream>>>(
        xb, Wint, (int)NB, 3 * d, d, 1, nullptr, Vb, Qb, Lb, lb);
    // 4) chunked scan
    scan_phase1<<<dim3(16, C), 256, 0, stream>>>(Lb, Vb, Sl, P, L);
    scan_phase2<<<dim3(64), 256, 0, stream>>>(Sl, P, Sini, C);
    unsigned short* ob = xb;  // xb dead after GEMM1; reuse as o
    scan_phase3<<<dim3(16, C), 256, 0, stream>>>(Lb, Vb, Qb, Sini, ob, L);
    // 5) GEMM2 -> fp32 output
    const int nwg2 = (d / BN) * (int)(NB / BM);       // 4 * 128 = 512 (%8==0)
    gemm_bf16<<<dim3(nwg2), 512, 0, stream>>>(
        ob, Wot, (int)NB, d, d, 0, out, nullptr, nullptr, nullptr, nullptr);
}